// Round 2
// baseline (1702.298 us; speedup 1.0000x reference)
//
#include <hip/hip_runtime.h>
#include <math.h>

// ---------------------------------------------------------------------------
// conv1: x[512][1][64][64] -> relu -> maxpool2 -> a1[512][16][32][32]
// thread per pooled output pixel
__global__ void k_conv1(const float* __restrict__ x, const float* __restrict__ w,
                        const float* __restrict__ bias, float* __restrict__ out) {
  int idx = blockIdx.x * 256 + threadIdx.x;
  int ox = idx & 31, oy = (idx >> 5) & 31, oc = (idx >> 10) & 15, n = idx >> 14;
  const float* im = x + n * 4096;
  float wv[9];
#pragma unroll
  for (int i = 0; i < 9; ++i) wv[i] = w[oc * 9 + i];
  float bs = bias[oc];
  float m = 0.f;  // relu(v) >= 0 so 0 is a safe identity for max-of-relu
#pragma unroll
  for (int dy = 0; dy < 2; ++dy)
#pragma unroll
    for (int dx = 0; dx < 2; ++dx) {
      int cy = oy * 2 + dy, cx = ox * 2 + dx;
      float s = bs;
#pragma unroll
      for (int ky = 0; ky < 3; ++ky) {
        int yy = cy + ky - 1;
        if (yy < 0 || yy >= 64) continue;
#pragma unroll
        for (int kx = 0; kx < 3; ++kx) {
          int xx = cx + kx - 1;
          if (xx < 0 || xx >= 64) continue;
          s += im[yy * 64 + xx] * wv[ky * 3 + kx];
        }
      }
      m = fmaxf(m, fmaxf(s, 0.f));
    }
  out[idx] = m;
}

// ---------------------------------------------------------------------------
// conv2: a1[512][16][32][32] -> relu -> maxpool2 -> a2[512][32][16][16]
// block = (n, oc), 256 threads = 16x16 pooled pixels; input staged in LDS in
// two 8-channel halves (32 KB each)
__global__ void k_conv2(const float* __restrict__ a1, const float* __restrict__ w,
                        const float* __restrict__ bias, float* __restrict__ out) {
  __shared__ float ins[8 * 1024];
  __shared__ float wl[144];
  int n = blockIdx.x, oc = blockIdx.y;
  int tid = threadIdx.x;
  int ox = tid & 15, oy = tid >> 4;
  if (tid < 144) wl[tid] = w[oc * 144 + tid];
  float acc[2][2] = {{0.f, 0.f}, {0.f, 0.f}};
  for (int ch = 0; ch < 16; ch += 8) {
    __syncthreads();  // also covers wl on first pass / ins reads on later passes
    const float* src = a1 + n * 16384 + ch * 1024;
    for (int i = tid; i < 8192; i += 256) ins[i] = src[i];
    __syncthreads();
    for (int c = 0; c < 8; ++c) {
      const float* wp = &wl[(ch + c) * 9];
      const float* ip = &ins[c * 1024];
#pragma unroll
      for (int dy = 0; dy < 2; ++dy)
#pragma unroll
        for (int dx = 0; dx < 2; ++dx) {
          int cy = oy * 2 + dy, cx = ox * 2 + dx;
          float s = 0.f;
#pragma unroll
          for (int ky = 0; ky < 3; ++ky) {
            int yy = cy + ky - 1;
            if (yy < 0 || yy >= 32) continue;
#pragma unroll
            for (int kx = 0; kx < 3; ++kx) {
              int xx = cx + kx - 1;
              if (xx < 0 || xx >= 32) continue;
              s += ip[yy * 32 + xx] * wp[ky * 3 + kx];
            }
          }
          acc[dy][dx] += s;
        }
    }
  }
  float m = fmaxf(fmaxf(acc[0][0], acc[0][1]), fmaxf(acc[1][0], acc[1][1]));
  m = fmaxf(m + bias[oc], 0.f);
  out[(n * 32 + oc) * 256 + oy * 16 + ox] = m;
}

// ---------------------------------------------------------------------------
// conv3: a2[512][32][16][16] -> relu -> mean(HW) -> embT[16][256][32]
// block = (n, group of 8 oc), 256 threads = 16x16 pixels.
// n = b*16 + t; writes transposed emb for the LSTM's coalesced [k][b] reads.
__global__ void k_conv3(const float* __restrict__ a2, const float* __restrict__ w,
                        const float* __restrict__ bias, float* __restrict__ embT) {
  __shared__ float ins[32 * 256];
  __shared__ float wl[8 * 288];
  __shared__ float red[32];
  int n = blockIdx.x, ocg = blockIdx.y;
  int tid = threadIdx.x;
  int ox = tid & 15, oy = (tid >> 4) & 15;
  const float* src = a2 + n * 8192;
  for (int i = tid; i < 8192; i += 256) ins[i] = src[i];
  const float* wsrc = w + ocg * 8 * 288;
  for (int i = tid; i < 2304; i += 256) wl[i] = wsrc[i];
  __syncthreads();
  float acc[8] = {0.f, 0.f, 0.f, 0.f, 0.f, 0.f, 0.f, 0.f};
  for (int c = 0; c < 32; ++c) {
    const float* ip = &ins[c * 256];
#pragma unroll
    for (int ky = 0; ky < 3; ++ky) {
      int yy = oy + ky - 1;
      if (yy < 0 || yy >= 16) continue;
#pragma unroll
      for (int kx = 0; kx < 3; ++kx) {
        int xx = ox + kx - 1;
        if (xx < 0 || xx >= 16) continue;
        float v = ip[yy * 16 + xx];
#pragma unroll
        for (int j = 0; j < 8; ++j) acc[j] += v * wl[j * 288 + c * 9 + ky * 3 + kx];
      }
    }
  }
  int bb = n >> 4, tt = n & 15;
  int lane = tid & 63, wv = tid >> 6;
#pragma unroll
  for (int j = 0; j < 8; ++j) {
    float v = fmaxf(acc[j] + bias[ocg * 8 + j], 0.f);
#pragma unroll
    for (int off = 32; off; off >>= 1) v += __shfl_down(v, off, 64);
    if (lane == 0) red[wv * 8 + j] = v;
  }
  __syncthreads();
  if (tid < 8) {
    float s = red[tid] + red[8 + tid] + red[16 + tid] + red[24 + tid];
    embT[(tt * 256 + (ocg * 8 + tid)) * 32 + bb] = s * (1.f / 256.f);
  }
}

// ---------------------------------------------------------------------------
// weight transpose: W[fan][512] -> WT[512][fan], 8 arrays in one launch
struct TPtrs { const float* in[8]; float* out[8]; };

__global__ void k_transpose(TPtrs p) {
  __shared__ float tile[32][33];
  int z = blockIdx.z;
  int fan = (z < 4) ? 768 : 1024;
  int k0 = blockIdx.x * 32, h0 = blockIdx.y * 32;
  if (k0 >= fan) return;
  const float* in = p.in[z];
  float* out = p.out[z];
  int tx = threadIdx.x, ty = threadIdx.y;  // 32 x 8
  for (int r = 0; r < 32; r += 8)
    tile[ty + r][tx] = in[(k0 + ty + r) * 512 + h0 + tx];
  __syncthreads();
  for (int r = 0; r < 32; r += 8)
    out[(h0 + ty + r) * fan + k0 + tx] = tile[tx][ty + r];
}

// ---------------------------------------------------------------------------
// one LSTM (layer, step): gates + activations + c/h update fused.
// grid 256 blocks x 512 threads; block owns h pair {2*bk, 2*bk+1} x 4 gates;
// the 8 transposed weight rows are staged in LDS so every weight is read from
// HBM/L2 exactly once per step. comb is read transposed [k][b] (coalesced,
// broadcast across the 8 column-groups). h double-buffered across steps.
template <int IN>
__global__ __launch_bounds__(512) void k_lstm(
    const float* __restrict__ xT, const float* __restrict__ hinT,
    float* __restrict__ houtT, float* __restrict__ cT,
    const float* __restrict__ WfT, const float* __restrict__ WiT,
    const float* __restrict__ WgT, const float* __restrict__ WoT,
    const float* __restrict__ bf, const float* __restrict__ bi,
    const float* __restrict__ bg, const float* __restrict__ bo) {
  constexpr int FAN = IN + 512;
  __shared__ __align__(16) float wl[8 * FAN];  // 24/32 KB, float4-accessed
  __shared__ float gsum[8][2][32];
  const int tid = threadIdx.x;
  const int h0 = blockIdx.x * 2;
  {
    const float* srcs[4] = {WfT, WiT, WgT, WoT};
    constexpr int R4 = FAN / 4;
    for (int i = tid; i < 8 * R4; i += 512) {
      int row = i / R4, c4 = i - row * R4;
      ((float4*)wl)[row * R4 + c4] =
          ((const float4*)srcs[row >> 1])[(h0 + (row & 1)) * R4 + c4];
    }
  }
  __syncthreads();
  const int c = tid >> 6, half = (tid >> 5) & 1, b = tid & 31;
  const float* wrow = wl + c * FAN;
  float a0 = 0.f, a1 = 0.f;
#pragma unroll 4
  for (int i = 0; i < IN / 2; i += 2) {
    int k0 = 2 * i + half;
    a0 += xT[k0 * 32 + b] * wrow[k0];
    a1 += xT[(k0 + 2) * 32 + b] * wrow[k0 + 2];
  }
#pragma unroll 4
  for (int i = IN / 2; i < FAN / 2; i += 2) {
    int k0 = 2 * i + half;
    a0 += hinT[(k0 - IN) * 32 + b] * wrow[k0];
    a1 += hinT[(k0 + 2 - IN) * 32 + b] * wrow[k0 + 2];
  }
  gsum[c][half][b] = a0 + a1;
  __syncthreads();
  if (tid < 64) {
    const int hh = tid >> 5, b2 = tid & 31, h = h0 + hh;
    float fp = gsum[hh][0][b2] + gsum[hh][1][b2] + bf[h];
    float ipre = gsum[2 + hh][0][b2] + gsum[2 + hh][1][b2] + bi[h];
    float gp = gsum[4 + hh][0][b2] + gsum[4 + hh][1][b2] + bg[h];
    float op = gsum[6 + hh][0][b2] + gsum[6 + hh][1][b2] + bo[h];
    float ft = 1.f / (1.f + expf(-fp));
    float it = 1.f / (1.f + expf(-ipre));
    float gt = tanhf(gp);
    float ot = 1.f / (1.f + expf(-op));
    float cn = ft * cT[h * 32 + b2] + it * gt;
    cT[h * 32 + b2] = cn;
    houtT[h * 32 + b2] = ot * tanhf(cn);
  }
}

// ---------------------------------------------------------------------------
// classifier: h[512] -> 128 relu -> 64 relu -> 6.  block per batch row.
__global__ void k_cls(const float* __restrict__ h1T, const float* __restrict__ cw1,
                      const float* __restrict__ cb1, const float* __restrict__ cw2,
                      const float* __restrict__ cb2, const float* __restrict__ cw3,
                      const float* __restrict__ cb3, float* __restrict__ out) {
  __shared__ float hv[512];
  __shared__ float y1[128];
  __shared__ float y2[64];
  int b = blockIdx.x, tid = threadIdx.x;  // 128 threads
  for (int i = tid; i < 512; i += 128) hv[i] = h1T[i * 32 + b];
  __syncthreads();
  float s = cb1[tid];
  for (int k = 0; k < 512; ++k) s += hv[k] * cw1[k * 128 + tid];
  y1[tid] = fmaxf(s, 0.f);
  __syncthreads();
  if (tid < 64) {
    float s2 = cb2[tid];
    for (int k = 0; k < 128; ++k) s2 += y1[k] * cw2[k * 64 + tid];
    y2[tid] = fmaxf(s2, 0.f);
  }
  __syncthreads();
  if (tid < 6) {
    float s3 = cb3[tid];
    for (int k = 0; k < 64; ++k) s3 += y2[k] * cw3[k * 6 + tid];
    out[b * 6 + tid] = s3;
  }
}

// ---------------------------------------------------------------------------
// Workspace layout (floats):
//   region0: a1 [512*16*32*32 = 8,388,608]   -- dead after conv2;
//            wt [3,670,016] ALIASES region0  -- written by k_transpose AFTER conv3
//   a2   = ws + 8,388,608   [512*32*16*16 = 4,194,304]   (round-1 bug: was 2,097,152)
//   embT = ws + 12,582,912  [16*256*32     =   131,072]
//   hc   = ws + 12,713,984  [6*S           =    98,304]
//   total 12,812,288 floats = 51.25 MB
extern "C" void kernel_launch(void* const* d_in, const int* in_sizes, int n_in,
                              void* d_out, int out_size, void* d_ws, size_t ws_size,
                              hipStream_t stream) {
  const float* x  = (const float*)d_in[0];
  const float* w1 = (const float*)d_in[1];
  const float* b1 = (const float*)d_in[2];
  const float* w2 = (const float*)d_in[3];
  const float* b2 = (const float*)d_in[4];
  const float* w3 = (const float*)d_in[5];
  const float* b3 = (const float*)d_in[6];
  const float* cw1 = (const float*)d_in[23];
  const float* cb1 = (const float*)d_in[24];
  const float* cw2 = (const float*)d_in[25];
  const float* cb2 = (const float*)d_in[26];
  const float* cw3 = (const float*)d_in[27];
  const float* cb3 = (const float*)d_in[28];

  float* ws = (float*)d_ws;
  float* a1   = ws;                   // 8,388,608 f (dead after conv2)
  float* wt   = ws;                   // 3,670,016 f (aliases a1; written after conv3)
  float* a2   = ws + 8388608;         // 4,194,304 f
  float* embT = ws + 12582912;        //   131,072 f
  float* hc   = ws + 12713984;        //    98,304 f
  const int S = 16384;                // 512*32

  // zero h0(p0), h1(p0), c0, c1 (contiguous at hc)
  hipMemsetAsync(hc, 0, (size_t)4 * S * sizeof(float), stream);

  k_conv1<<<32768, 256, 0, stream>>>(x, w1, b1, a1);
  k_conv2<<<dim3(512, 32), 256, 0, stream>>>(a1, w2, b2, a2);
  k_conv3<<<dim3(512, 32), 256, 0, stream>>>(a2, w3, b3, embT);

  // weight transposes W[fan][512] -> WT[512][fan]; runs after conv2/conv3 so
  // clobbering the a1 region is safe (stream-ordered).
  TPtrs tp;
  for (int g = 0; g < 4; ++g) {
    tp.in[g]      = (const float*)d_in[7 + 2 * g];       // Wf0,Wi0,Wg0,Wo0
    tp.out[g]     = wt + g * (512 * 768);
    tp.in[4 + g]  = (const float*)d_in[15 + 2 * g];      // Wf1,Wi1,Wg1,Wo1
    tp.out[4 + g] = wt + 4 * (512 * 768) + g * (512 * 1024);
  }
  k_transpose<<<dim3(32, 16, 8), dim3(32, 8), 0, stream>>>(tp);

  const float* wl0[4] = {wt, wt + 393216, wt + 786432, wt + 1179648};
  float* l1base = wt + 1572864;
  const float* wl1[4] = {l1base, l1base + 524288, l1base + 1048576, l1base + 1572864};

  for (int t = 0; t < 16; ++t) {
    int pi = t & 1, po = 1 - pi;
    float* h0i = hc + (pi ? 4 * S : 0);
    float* h0o = hc + (po ? 4 * S : 0);
    float* h1i = hc + S + (pi ? 4 * S : 0);
    float* h1o = hc + S + (po ? 4 * S : 0);
    k_lstm<256><<<256, 512, 0, stream>>>(
        embT + t * 256 * 32, h0i, h0o, hc + 2 * S,
        wl0[0], wl0[1], wl0[2], wl0[3],
        (const float*)d_in[8], (const float*)d_in[10],
        (const float*)d_in[12], (const float*)d_in[14]);
    k_lstm<512><<<256, 512, 0, stream>>>(
        h0o, h1i, h1o, hc + 3 * S,
        wl1[0], wl1[1], wl1[2], wl1[3],
        (const float*)d_in[16], (const float*)d_in[18],
        (const float*)d_in[20], (const float*)d_in[22]);
  }

  // final top-layer h is at buffer parity (15+1)%2 == 0 -> hc + S
  k_cls<<<32, 128, 0, stream>>>(hc + S, cw1, cb1, cw2, cb2, cw3, cb3,
                                (float*)d_out);
}

// Round 3
// 939.577 us; speedup vs baseline: 1.8118x; 1.8118x over previous
//
#include <hip/hip_runtime.h>
#include <math.h>

// ---------------------------------------------------------------------------
// conv1: x[512][1][64][64] -> relu -> maxpool2 -> a1[512][16][32][32]
// thread per pooled output pixel (unchanged)
__global__ void k_conv1(const float* __restrict__ x, const float* __restrict__ w,
                        const float* __restrict__ bias, float* __restrict__ out) {
  int idx = blockIdx.x * 256 + threadIdx.x;
  int ox = idx & 31, oy = (idx >> 5) & 31, oc = (idx >> 10) & 15, n = idx >> 14;
  const float* im = x + n * 4096;
  float wv[9];
#pragma unroll
  for (int i = 0; i < 9; ++i) wv[i] = w[oc * 9 + i];
  float bs = bias[oc];
  float m = 0.f;
#pragma unroll
  for (int dy = 0; dy < 2; ++dy)
#pragma unroll
    for (int dx = 0; dx < 2; ++dx) {
      int cy = oy * 2 + dy, cx = ox * 2 + dx;
      float s = bs;
#pragma unroll
      for (int ky = 0; ky < 3; ++ky) {
        int yy = cy + ky - 1;
        if (yy < 0 || yy >= 64) continue;
#pragma unroll
        for (int kx = 0; kx < 3; ++kx) {
          int xx = cx + kx - 1;
          if (xx < 0 || xx >= 64) continue;
          s += im[yy * 64 + xx] * wv[ky * 3 + kx];
        }
      }
      m = fmaxf(m, fmaxf(s, 0.f));
    }
  out[idx] = m;
}

// ---------------------------------------------------------------------------
// weight prep: w2t[c][tap][32oc], w3t[c][tap][256oc]  (scalar-load layouts)
__global__ void k_prep_w(const float* __restrict__ w2, float* __restrict__ w2t,
                         const float* __restrict__ w3, float* __restrict__ w3t) {
  int id = blockIdx.x * 256 + threadIdx.x;
  if (id < 73728) {  // 288 * 256
    int ct = id >> 8, oc = id & 255;
    int c = ct / 9, tap = ct - 9 * c;
    w3t[id] = w3[(oc * 32 + c) * 9 + tap];
  }
  if (id < 4608) {   // 144 * 32
    int ct = id >> 5, oc = id & 31;
    int c = ct / 9, tap = ct - 9 * c;
    w2t[id] = w2[(oc * 16 + c) * 9 + tap];
  }
}

// ---------------------------------------------------------------------------
// conv2: a1[512][16][32][32] -> relu -> maxpool2 -> a2[n][px=256][oc=32]
// block = (n, ocg of 16 oc), 256 threads = 256 pooled px.
// thread: 2x2 conv px (one pooled px) x 16 oc; weights via uniform scalar
// loads from w2t; input windows from LDS (16 b32/channel, predicated borders).
__global__ __launch_bounds__(256) void k_conv2(
    const float* __restrict__ a1, const float* __restrict__ w2t,
    const float* __restrict__ bias, float* __restrict__ a2) {
  __shared__ __align__(16) float ins[8 * 1024];  // 8 channels of 32x32
  int n = blockIdx.x, ocg = blockIdx.y;
  int tid = threadIdx.x;
  int py = tid >> 4, px = tid & 15;
  int y0 = 2 * py - 1, x0 = 2 * px - 1;
  float acc[16][4] = {};
  const float* wb = w2t + ocg * 16;  // + (c*9+tap)*32 + j
  for (int ph = 0; ph < 2; ++ph) {
    __syncthreads();
    const float4* src = (const float4*)(a1 + n * 16384 + ph * 8192);
    for (int i = tid; i < 2048; i += 256) ((float4*)ins)[i] = src[i];
    __syncthreads();
    for (int c = 0; c < 8; ++c) {
      float wv[4][4];
#pragma unroll
      for (int r = 0; r < 4; ++r) {
        int y = y0 + r;
        bool vy = (y >= 0) && (y < 32);
        int yc = vy ? y : 0;
#pragma unroll
        for (int cc = 0; cc < 4; ++cc) {
          int xx = x0 + cc;
          bool vx = (xx >= 0) && (xx < 32);
          int xc = vx ? xx : 0;
          float t = ins[c * 1024 + yc * 32 + xc];
          wv[r][cc] = (vy && vx) ? t : 0.f;
        }
      }
      int ch = ph * 8 + c;
#pragma unroll
      for (int ky = 0; ky < 3; ++ky)
#pragma unroll
        for (int kx = 0; kx < 3; ++kx) {
          const float* w16 = wb + (ch * 9 + ky * 3 + kx) * 32;
#pragma unroll
          for (int i = 0; i < 4; ++i) {
            float vv = wv[(i >> 1) + ky][(i & 1) + kx];
#pragma unroll
            for (int j = 0; j < 16; ++j) acc[j][i] += vv * w16[j];
          }
        }
    }
  }
  const float* bp = bias + ocg * 16;
  float4 o[4];
#pragma unroll
  for (int j = 0; j < 16; ++j) {
    float m = fmaxf(fmaxf(acc[j][0], acc[j][1]), fmaxf(acc[j][2], acc[j][3]));
    ((float*)o)[j] = fmaxf(m + bp[j], 0.f);
  }
  float4* dst = (float4*)(a2 + (size_t)(n * 256 + tid) * 32 + ocg * 16);
#pragma unroll
  for (int q = 0; q < 4; ++q) dst[q] = o[q];
}

// ---------------------------------------------------------------------------
// conv3: a2[n][px][32ch] -> relu -> mean(HW) -> embT[16][256][32]
// block = (n, ocb of 32 oc), 256 threads = 4 waves x (64 lanes = 4x1 px strips).
// LDS: zero-haloed [18*18][32ch] tile, row stride 36 dwords -> conflict-free
// ds_read_b128. Weights w3t[c][tap][oc] via wave-uniform scalar loads.
__global__ __launch_bounds__(256) void k_conv3(
    const float* __restrict__ a2, const float* __restrict__ w3t,
    const float* __restrict__ bias, float* __restrict__ embT) {
  __shared__ __align__(16) float ins[324 * 36];  // 46656 B
  int n = blockIdx.x, ocb = blockIdx.y;
  int tid = threadIdx.x;
  // zero fill (borders), then interior
  for (int i = tid; i < 2916; i += 256) ((float4*)ins)[i] = float4{0.f, 0.f, 0.f, 0.f};
  __syncthreads();
  const float4* src = (const float4*)(a2 + (size_t)n * 8192);
  for (int i = tid; i < 2048; i += 256) {
    int px = i >> 3, cg = i & 7;
    int p = ((px >> 4) + 1) * 18 + (px & 15) + 1;
    ((float4*)ins)[p * 9 + cg] = src[i];
  }
  __syncthreads();
  int wvid = __builtin_amdgcn_readfirstlane(tid >> 6);  // force SGPR (scalar weight loads)
  int lane = tid & 63;
  int tr = lane >> 4, tc = lane & 15;  // 4-row strip at rows 4tr.., col tc
  float acc[4][8] = {};
  const float* wbase = w3t + ocb * 32 + wvid * 8;  // + ((c)*9+tap)*256 + j
  for (int cg = 0; cg < 8; ++cg) {
    float4 v[6][3];
#pragma unroll
    for (int dr = 0; dr < 6; ++dr)
#pragma unroll
      for (int dc = 0; dc < 3; ++dc)
        v[dr][dc] = ((const float4*)ins)[((4 * tr + dr) * 18 + tc + dc) * 9 + cg];
#pragma unroll
    for (int ky = 0; ky < 3; ++ky)
#pragma unroll
      for (int kx = 0; kx < 3; ++kx)
#pragma unroll
        for (int c = 0; c < 4; ++c) {
          const float* w8 = wbase + ((cg * 4 + c) * 9 + ky * 3 + kx) * 256;
#pragma unroll
          for (int i = 0; i < 4; ++i) {
            float vv = ((const float*)&v[i + ky][kx])[c];
#pragma unroll
            for (int j = 0; j < 8; ++j) acc[i][j] += vv * w8[j];
          }
        }
  }
  // epilogue: +bias, relu, mean over 256 px (4 in-thread + 64-lane reduce)
  const float* bp = bias + ocb * 32 + wvid * 8;
  int bb = n >> 4, tt = n & 15;
#pragma unroll
  for (int j = 0; j < 8; ++j) {
    float bj = bp[j];
    float s = 0.f;
#pragma unroll
    for (int i = 0; i < 4; ++i) s += fmaxf(acc[i][j] + bj, 0.f);
#pragma unroll
    for (int off = 32; off; off >>= 1) s += __shfl_down(s, off, 64);
    if (lane == 0)
      embT[(size_t)(tt * 256 + ocb * 32 + wvid * 8 + j) * 32 + bb] = s * (1.f / 256.f);
  }
}

// ---------------------------------------------------------------------------
// weight transpose: W[fan][512] -> WT[512][fan], 8 arrays in one launch
struct TPtrs { const float* in[8]; float* out[8]; };

__global__ void k_transpose(TPtrs p) {
  __shared__ float tile[32][33];
  int z = blockIdx.z;
  int fan = (z < 4) ? 768 : 1024;
  int k0 = blockIdx.x * 32, h0 = blockIdx.y * 32;
  if (k0 >= fan) return;
  const float* in = p.in[z];
  float* out = p.out[z];
  int tx = threadIdx.x, ty = threadIdx.y;  // 32 x 8
  for (int r = 0; r < 32; r += 8)
    tile[ty + r][tx] = in[(k0 + ty + r) * 512 + h0 + tx];
  __syncthreads();
  for (int r = 0; r < 32; r += 8)
    out[(h0 + ty + r) * fan + k0 + tx] = tile[tx][ty + r];
}

// ---------------------------------------------------------------------------
// one LSTM (layer, step) — unchanged from round 2 (passing)
template <int IN>
__global__ __launch_bounds__(512) void k_lstm(
    const float* __restrict__ xT, const float* __restrict__ hinT,
    float* __restrict__ houtT, float* __restrict__ cT,
    const float* __restrict__ WfT, const float* __restrict__ WiT,
    const float* __restrict__ WgT, const float* __restrict__ WoT,
    const float* __restrict__ bf, const float* __restrict__ bi,
    const float* __restrict__ bg, const float* __restrict__ bo) {
  constexpr int FAN = IN + 512;
  __shared__ __align__(16) float wl[8 * FAN];
  __shared__ float gsum[8][2][32];
  const int tid = threadIdx.x;
  const int h0 = blockIdx.x * 2;
  {
    const float* srcs[4] = {WfT, WiT, WgT, WoT};
    constexpr int R4 = FAN / 4;
    for (int i = tid; i < 8 * R4; i += 512) {
      int row = i / R4, c4 = i - row * R4;
      ((float4*)wl)[row * R4 + c4] =
          ((const float4*)srcs[row >> 1])[(h0 + (row & 1)) * R4 + c4];
    }
  }
  __syncthreads();
  const int c = tid >> 6, half = (tid >> 5) & 1, b = tid & 31;
  const float* wrow = wl + c * FAN;
  float a0 = 0.f, a1 = 0.f;
#pragma unroll 4
  for (int i = 0; i < IN / 2; i += 2) {
    int k0 = 2 * i + half;
    a0 += xT[k0 * 32 + b] * wrow[k0];
    a1 += xT[(k0 + 2) * 32 + b] * wrow[k0 + 2];
  }
#pragma unroll 4
  for (int i = IN / 2; i < FAN / 2; i += 2) {
    int k0 = 2 * i + half;
    a0 += hinT[(k0 - IN) * 32 + b] * wrow[k0];
    a1 += hinT[(k0 + 2 - IN) * 32 + b] * wrow[k0 + 2];
  }
  gsum[c][half][b] = a0 + a1;
  __syncthreads();
  if (tid < 64) {
    const int hh = tid >> 5, b2 = tid & 31, h = h0 + hh;
    float fp = gsum[hh][0][b2] + gsum[hh][1][b2] + bf[h];
    float ipre = gsum[2 + hh][0][b2] + gsum[2 + hh][1][b2] + bi[h];
    float gp = gsum[4 + hh][0][b2] + gsum[4 + hh][1][b2] + bg[h];
    float op = gsum[6 + hh][0][b2] + gsum[6 + hh][1][b2] + bo[h];
    float ft = 1.f / (1.f + expf(-fp));
    float it = 1.f / (1.f + expf(-ipre));
    float gt = tanhf(gp);
    float ot = 1.f / (1.f + expf(-op));
    float cn = ft * cT[h * 32 + b2] + it * gt;
    cT[h * 32 + b2] = cn;
    houtT[h * 32 + b2] = ot * tanhf(cn);
  }
}

// ---------------------------------------------------------------------------
// classifier (unchanged)
__global__ void k_cls(const float* __restrict__ h1T, const float* __restrict__ cw1,
                      const float* __restrict__ cb1, const float* __restrict__ cw2,
                      const float* __restrict__ cb2, const float* __restrict__ cw3,
                      const float* __restrict__ cb3, float* __restrict__ out) {
  __shared__ float hv[512];
  __shared__ float y1[128];
  __shared__ float y2[64];
  int b = blockIdx.x, tid = threadIdx.x;
  for (int i = tid; i < 512; i += 128) hv[i] = h1T[i * 32 + b];
  __syncthreads();
  float s = cb1[tid];
  for (int k = 0; k < 512; ++k) s += hv[k] * cw1[k * 128 + tid];
  y1[tid] = fmaxf(s, 0.f);
  __syncthreads();
  if (tid < 64) {
    float s2 = cb2[tid];
    for (int k = 0; k < 128; ++k) s2 += y1[k] * cw2[k * 64 + tid];
    y2[tid] = fmaxf(s2, 0.f);
  }
  __syncthreads();
  if (tid < 6) {
    float s3 = cb3[tid];
    for (int k = 0; k < 64; ++k) s3 += y2[k] * cw3[k * 6 + tid];
    out[b * 6 + tid] = s3;
  }
}

// ---------------------------------------------------------------------------
// Workspace layout (floats):
//   region0: a1 [8,388,608] (dead after conv2); wt [3,670,016] aliases it
//   a2   = ws + 8,388,608   [512*256*32 = 4,194,304]  layout [n][px][oc]
//   embT = ws + 12,582,912  [131,072]
//   hc   = ws + 12,713,984  [98,304]
//   w2t  = ws + 12,812,288  [4,608]
//   w3t  = ws + 12,816,896  [73,728]
//   total 12,890,624 f = 51.6 MB
extern "C" void kernel_launch(void* const* d_in, const int* in_sizes, int n_in,
                              void* d_out, int out_size, void* d_ws, size_t ws_size,
                              hipStream_t stream) {
  const float* x  = (const float*)d_in[0];
  const float* w1 = (const float*)d_in[1];
  const float* b1 = (const float*)d_in[2];
  const float* w2 = (const float*)d_in[3];
  const float* b2 = (const float*)d_in[4];
  const float* w3 = (const float*)d_in[5];
  const float* b3 = (const float*)d_in[6];
  const float* cw1 = (const float*)d_in[23];
  const float* cb1 = (const float*)d_in[24];
  const float* cw2 = (const float*)d_in[25];
  const float* cb2 = (const float*)d_in[26];
  const float* cw3 = (const float*)d_in[27];
  const float* cb3 = (const float*)d_in[28];

  float* ws = (float*)d_ws;
  float* a1   = ws;
  float* wt   = ws;                    // aliases a1; written after conv3
  float* a2   = ws + 8388608;
  float* embT = ws + 12582912;
  float* hc   = ws + 12713984;
  float* w2t  = ws + 12812288;
  float* w3t  = ws + 12816896;
  const int S = 16384;  // 512*32

  hipMemsetAsync(hc, 0, (size_t)4 * S * sizeof(float), stream);
  k_prep_w<<<288, 256, 0, stream>>>(w2, w2t, w3, w3t);

  k_conv1<<<32768, 256, 0, stream>>>(x, w1, b1, a1);
  k_conv2<<<dim3(512, 2), 256, 0, stream>>>(a1, w2t, b2, a2);
  k_conv3<<<dim3(512, 8), 256, 0, stream>>>(a2, w3t, b3, embT);

  TPtrs tp;
  for (int g = 0; g < 4; ++g) {
    tp.in[g]      = (const float*)d_in[7 + 2 * g];
    tp.out[g]     = wt + g * (512 * 768);
    tp.in[4 + g]  = (const float*)d_in[15 + 2 * g];
    tp.out[4 + g] = wt + 4 * (512 * 768) + g * (512 * 1024);
  }
  k_transpose<<<dim3(32, 16, 8), dim3(32, 8), 0, stream>>>(tp);

  const float* wl0[4] = {wt, wt + 393216, wt + 786432, wt + 1179648};
  float* l1base = wt + 1572864;
  const float* wl1[4] = {l1base, l1base + 524288, l1base + 1048576, l1base + 1572864};

  for (int t = 0; t < 16; ++t) {
    int pi = t & 1, po = 1 - pi;
    float* h0i = hc + (pi ? 4 * S : 0);
    float* h0o = hc + (po ? 4 * S : 0);
    float* h1i = hc + S + (pi ? 4 * S : 0);
    float* h1o = hc + S + (po ? 4 * S : 0);
    k_lstm<256><<<256, 512, 0, stream>>>(
        embT + t * 256 * 32, h0i, h0o, hc + 2 * S,
        wl0[0], wl0[1], wl0[2], wl0[3],
        (const float*)d_in[8], (const float*)d_in[10],
        (const float*)d_in[12], (const float*)d_in[14]);
    k_lstm<512><<<256, 512, 0, stream>>>(
        h0o, h1i, h1o, hc + 3 * S,
        wl1[0], wl1[1], wl1[2], wl1[3],
        (const float*)d_in[16], (const float*)d_in[18],
        (const float*)d_in[20], (const float*)d_in[22]);
  }

  k_cls<<<32, 128, 0, stream>>>(hc + S, cw1, cb1, cw2, cb2, cw3, cb3,
                                (float*)d_out);
}

// Round 4
// 733.513 us; speedup vs baseline: 2.3207x; 1.2809x over previous
//
#include <hip/hip_runtime.h>
#include <math.h>

// ---------------------------------------------------------------------------
// conv1: x[512][1][64][64] -> relu -> maxpool2 -> a1[512][16][32][32]
__global__ void k_conv1(const float* __restrict__ x, const float* __restrict__ w,
                        const float* __restrict__ bias, float* __restrict__ out) {
  int idx = blockIdx.x * 256 + threadIdx.x;
  int ox = idx & 31, oy = (idx >> 5) & 31, oc = (idx >> 10) & 15, n = idx >> 14;
  const float* im = x + n * 4096;
  float wv[9];
#pragma unroll
  for (int i = 0; i < 9; ++i) wv[i] = w[oc * 9 + i];
  float bs = bias[oc];
  float m = 0.f;
#pragma unroll
  for (int dy = 0; dy < 2; ++dy)
#pragma unroll
    for (int dx = 0; dx < 2; ++dx) {
      int cy = oy * 2 + dy, cx = ox * 2 + dx;
      float s = bs;
#pragma unroll
      for (int ky = 0; ky < 3; ++ky) {
        int yy = cy + ky - 1;
        if (yy < 0 || yy >= 64) continue;
#pragma unroll
        for (int kx = 0; kx < 3; ++kx) {
          int xx = cx + kx - 1;
          if (xx < 0 || xx >= 64) continue;
          s += im[yy * 64 + xx] * wv[ky * 3 + kx];
        }
      }
      m = fmaxf(m, fmaxf(s, 0.f));
    }
  out[idx] = m;
}

// ---------------------------------------------------------------------------
// weight prep: w2t[c][tap][32oc], w3t[c][tap][256oc]  (scalar-load layouts)
__global__ void k_prep_w(const float* __restrict__ w2, float* __restrict__ w2t,
                         const float* __restrict__ w3, float* __restrict__ w3t) {
  int id = blockIdx.x * 256 + threadIdx.x;
  if (id < 73728) {  // 288 * 256
    int ct = id >> 8, oc = id & 255;
    int c = ct / 9, tap = ct - 9 * c;
    w3t[id] = w3[(oc * 32 + c) * 9 + tap];
  }
  if (id < 4608) {   // 144 * 32
    int ct = id >> 5, oc = id & 31;
    int c = ct / 9, tap = ct - 9 * c;
    w2t[id] = w2[(oc * 16 + c) * 9 + tap];
  }
}

// ---------------------------------------------------------------------------
// conv2: a1[512][16][32][32] -> relu -> maxpool2 -> a2[n][px=256][oc=32]
// (unchanged from round 3)
__global__ __launch_bounds__(256) void k_conv2(
    const float* __restrict__ a1, const float* __restrict__ w2t,
    const float* __restrict__ bias, float* __restrict__ a2) {
  __shared__ __align__(16) float ins[8 * 1024];
  int n = blockIdx.x, ocg = blockIdx.y;
  int tid = threadIdx.x;
  int py = tid >> 4, px = tid & 15;
  int y0 = 2 * py - 1, x0 = 2 * px - 1;
  float acc[16][4] = {};
  const float* wb = w2t + ocg * 16;
  for (int ph = 0; ph < 2; ++ph) {
    __syncthreads();
    const float4* src = (const float4*)(a1 + n * 16384 + ph * 8192);
    for (int i = tid; i < 2048; i += 256) ((float4*)ins)[i] = src[i];
    __syncthreads();
    for (int c = 0; c < 8; ++c) {
      float wv[4][4];
#pragma unroll
      for (int r = 0; r < 4; ++r) {
        int y = y0 + r;
        bool vy = (y >= 0) && (y < 32);
        int yc = vy ? y : 0;
#pragma unroll
        for (int cc = 0; cc < 4; ++cc) {
          int xx = x0 + cc;
          bool vx = (xx >= 0) && (xx < 32);
          int xc = vx ? xx : 0;
          float t = ins[c * 1024 + yc * 32 + xc];
          wv[r][cc] = (vy && vx) ? t : 0.f;
        }
      }
      int ch = ph * 8 + c;
#pragma unroll
      for (int ky = 0; ky < 3; ++ky)
#pragma unroll
        for (int kx = 0; kx < 3; ++kx) {
          const float* w16 = wb + (ch * 9 + ky * 3 + kx) * 32;
#pragma unroll
          for (int i = 0; i < 4; ++i) {
            float vv = wv[(i >> 1) + ky][(i & 1) + kx];
#pragma unroll
            for (int j = 0; j < 16; ++j) acc[j][i] += vv * w16[j];
          }
        }
    }
  }
  const float* bp = bias + ocg * 16;
  float4 o[4];
#pragma unroll
  for (int j = 0; j < 16; ++j) {
    float m = fmaxf(fmaxf(acc[j][0], acc[j][1]), fmaxf(acc[j][2], acc[j][3]));
    ((float*)o)[j] = fmaxf(m + bp[j], 0.f);
  }
  float4* dst = (float4*)(a2 + (size_t)(n * 256 + tid) * 32 + ocg * 16);
#pragma unroll
  for (int q = 0; q < 4; ++q) dst[q] = o[q];
}

// ---------------------------------------------------------------------------
// conv3 v3: a2[n][px][32ch] -> relu -> mean(HW) -> embT[16][256][32]
// Channel-split staging: 16 ch per phase, LDS [324 px][20 f] = 25.9 KB ->
// 6 blocks/CU (was 3 at 47 KB). Halo zeros written once, persist across
// phases (interior-only refill). Row stride 5 float4 (odd) keeps ds_read_b128
// at the minimal 2x/16-lane aliasing. Weights via wave-uniform scalar loads.
__global__ __launch_bounds__(256) void k_conv3(
    const float* __restrict__ a2, const float* __restrict__ w3t,
    const float* __restrict__ bias, float* __restrict__ embT) {
  __shared__ __align__(16) float ins[324 * 20];  // 25,920 B
  int n = blockIdx.x, ocb = blockIdx.y;
  int tid = threadIdx.x;
  for (int i = tid; i < 1620; i += 256) ((float4*)ins)[i] = float4{0.f, 0.f, 0.f, 0.f};
  int wvid = __builtin_amdgcn_readfirstlane(tid >> 6);
  int lane = tid & 63;
  int tr = lane >> 4, tc = lane & 15;
  float acc[4][8] = {};
  const float* wbase = w3t + ocb * 32 + wvid * 8;
  const float4* src = (const float4*)(a2 + (size_t)n * 8192);
  for (int hf = 0; hf < 2; ++hf) {
    __syncthreads();  // zero-fill done (hf=0) / prior-phase reads done (hf=1)
    for (int i = tid; i < 1024; i += 256) {
      int px = i >> 2, cg = i & 3;
      int p = ((px >> 4) + 1) * 18 + (px & 15) + 1;
      ((float4*)ins)[p * 5 + cg] = src[px * 8 + hf * 4 + cg];
    }
    __syncthreads();
    for (int cg = 0; cg < 4; ++cg) {
      float4 v[6][3];
#pragma unroll
      for (int dr = 0; dr < 6; ++dr)
#pragma unroll
        for (int dc = 0; dc < 3; ++dc)
          v[dr][dc] = ((const float4*)ins)[((4 * tr + dr) * 18 + tc + dc) * 5 + cg];
#pragma unroll
      for (int ky = 0; ky < 3; ++ky)
#pragma unroll
        for (int kx = 0; kx < 3; ++kx)
#pragma unroll
          for (int c = 0; c < 4; ++c) {
            const float* w8 = wbase + (((hf * 4 + cg) * 4 + c) * 9 + ky * 3 + kx) * 256;
#pragma unroll
            for (int i = 0; i < 4; ++i) {
              float vv = ((const float*)&v[i + ky][kx])[c];
#pragma unroll
              for (int j = 0; j < 8; ++j) acc[i][j] += vv * w8[j];
            }
          }
    }
  }
  const float* bp = bias + ocb * 32 + wvid * 8;
  int bb = n >> 4, tt = n & 15;
#pragma unroll
  for (int j = 0; j < 8; ++j) {
    float bj = bp[j];
    float s = 0.f;
#pragma unroll
    for (int i = 0; i < 4; ++i) s += fmaxf(acc[i][j] + bj, 0.f);
#pragma unroll
    for (int off = 32; off; off >>= 1) s += __shfl_down(s, off, 64);
    if (lane == 0)
      embT[(size_t)(tt * 256 + ocb * 32 + wvid * 8 + j) * 32 + bb] = s * (1.f / 256.f);
  }
}

// ---------------------------------------------------------------------------
// weight transpose: W[fan][512] -> WT[512][fan], 8 arrays in one launch
struct TPtrs { const float* in[8]; float* out[8]; };

__global__ void k_transpose(TPtrs p) {
  __shared__ float tile[32][33];
  int z = blockIdx.z;
  int fan = (z < 4) ? 768 : 1024;
  int k0 = blockIdx.x * 32, h0 = blockIdx.y * 32;
  if (k0 >= fan) return;
  const float* in = p.in[z];
  float* out = p.out[z];
  int tx = threadIdx.x, ty = threadIdx.y;  // 32 x 8
  for (int r = 0; r < 32; r += 8)
    tile[ty + r][tx] = in[(k0 + ty + r) * 512 + h0 + tx];
  __syncthreads();
  for (int r = 0; r < 32; r += 8)
    out[(h0 + ty + r) * fan + k0 + tx] = tile[tx][ty + r];
}

// ---------------------------------------------------------------------------
// LSTM step v2: thread owns a CONTIGUOUS k-half of its gate-row -> weights
// read as ds_read_b128 (4 MACs per DS instr; was 1 per scalar ds_read_b32).
template <int IN>
__global__ __launch_bounds__(512) void k_lstm(
    const float* __restrict__ xT, const float* __restrict__ hinT,
    float* __restrict__ houtT, float* __restrict__ cT,
    const float* __restrict__ WfT, const float* __restrict__ WiT,
    const float* __restrict__ WgT, const float* __restrict__ WoT,
    const float* __restrict__ bf, const float* __restrict__ bi,
    const float* __restrict__ bg, const float* __restrict__ bo) {
  constexpr int FAN = IN + 512;
  __shared__ __align__(16) float wl[8 * FAN];
  __shared__ float gsum[8][2][32];
  const int tid = threadIdx.x;
  const int h0 = blockIdx.x * 2;
  {
    const float* srcs[4] = {WfT, WiT, WgT, WoT};
    constexpr int R4 = FAN / 4;
    for (int i = tid; i < 8 * R4; i += 512) {
      int row = i / R4, q = i - row * R4;
      ((float4*)wl)[row * R4 + q] =
          ((const float4*)srcs[row >> 1])[(h0 + (row & 1)) * R4 + q];
    }
  }
  __syncthreads();
  const int c = tid >> 6, half = (tid >> 5) & 1, b = tid & 31;
  const float4* wrow4 = (const float4*)(wl + c * FAN + half * (FAN / 2));
  const int kbase = half * (FAN / 2);
  float a0 = 0.f, a1 = 0.f, a2 = 0.f, a3 = 0.f;
#pragma unroll 8
  for (int q = 0; q < FAN / 8; ++q) {
    float4 w = wrow4[q];
    int k0 = kbase + 4 * q;
    const float* xs = (k0 < IN) ? (xT + k0 * 32 + b) : (hinT + (k0 - IN) * 32 + b);
    a0 += w.x * xs[0];
    a1 += w.y * xs[32];
    a2 += w.z * xs[64];
    a3 += w.w * xs[96];
  }
  gsum[c][half][b] = (a0 + a1) + (a2 + a3);
  __syncthreads();
  if (tid < 64) {
    const int hh = tid >> 5, b2 = tid & 31, h = h0 + hh;
    float fp = gsum[hh][0][b2] + gsum[hh][1][b2] + bf[h];
    float ipre = gsum[2 + hh][0][b2] + gsum[2 + hh][1][b2] + bi[h];
    float gp = gsum[4 + hh][0][b2] + gsum[4 + hh][1][b2] + bg[h];
    float op = gsum[6 + hh][0][b2] + gsum[6 + hh][1][b2] + bo[h];
    float ft = 1.f / (1.f + expf(-fp));
    float it = 1.f / (1.f + expf(-ipre));
    float gt = tanhf(gp);
    float ot = 1.f / (1.f + expf(-op));
    float cn = ft * cT[h * 32 + b2] + it * gt;
    cT[h * 32 + b2] = cn;
    houtT[h * 32 + b2] = ot * tanhf(cn);
  }
}

// ---------------------------------------------------------------------------
// classifier (unchanged)
__global__ void k_cls(const float* __restrict__ h1T, const float* __restrict__ cw1,
                      const float* __restrict__ cb1, const float* __restrict__ cw2,
                      const float* __restrict__ cb2, const float* __restrict__ cw3,
                      const float* __restrict__ cb3, float* __restrict__ out) {
  __shared__ float hv[512];
  __shared__ float y1[128];
  __shared__ float y2[64];
  int b = blockIdx.x, tid = threadIdx.x;
  for (int i = tid; i < 512; i += 128) hv[i] = h1T[i * 32 + b];
  __syncthreads();
  float s = cb1[tid];
  for (int k = 0; k < 512; ++k) s += hv[k] * cw1[k * 128 + tid];
  y1[tid] = fmaxf(s, 0.f);
  __syncthreads();
  if (tid < 64) {
    float s2 = cb2[tid];
    for (int k = 0; k < 128; ++k) s2 += y1[k] * cw2[k * 64 + tid];
    y2[tid] = fmaxf(s2, 0.f);
  }
  __syncthreads();
  if (tid < 6) {
    float s3 = cb3[tid];
    for (int k = 0; k < 64; ++k) s3 += y2[k] * cw3[k * 6 + tid];
    out[b * 6 + tid] = s3;
  }
}

// ---------------------------------------------------------------------------
// Workspace layout (floats):
//   region0: a1 [8,388,608] (dead after conv2); wt [3,670,016] aliases it
//   a2   = ws + 8,388,608   [4,194,304]  layout [n][px][oc]
//   embT = ws + 12,582,912  [131,072]
//   hc   = ws + 12,713,984  [98,304]
//   w2t  = ws + 12,812,288  [4,608]
//   w3t  = ws + 12,816,896  [73,728]
extern "C" void kernel_launch(void* const* d_in, const int* in_sizes, int n_in,
                              void* d_out, int out_size, void* d_ws, size_t ws_size,
                              hipStream_t stream) {
  const float* x  = (const float*)d_in[0];
  const float* w1 = (const float*)d_in[1];
  const float* b1 = (const float*)d_in[2];
  const float* w2 = (const float*)d_in[3];
  const float* b2 = (const float*)d_in[4];
  const float* w3 = (const float*)d_in[5];
  const float* b3 = (const float*)d_in[6];
  const float* cw1 = (const float*)d_in[23];
  const float* cb1 = (const float*)d_in[24];
  const float* cw2 = (const float*)d_in[25];
  const float* cb2 = (const float*)d_in[26];
  const float* cw3 = (const float*)d_in[27];
  const float* cb3 = (const float*)d_in[28];

  float* ws = (float*)d_ws;
  float* a1   = ws;
  float* wt   = ws;                    // aliases a1; written after conv3
  float* a2   = ws + 8388608;
  float* embT = ws + 12582912;
  float* hc   = ws + 12713984;
  float* w2t  = ws + 12812288;
  float* w3t  = ws + 12816896;
  const int S = 16384;  // 512*32

  hipMemsetAsync(hc, 0, (size_t)4 * S * sizeof(float), stream);
  k_prep_w<<<288, 256, 0, stream>>>(w2, w2t, w3, w3t);

  k_conv1<<<32768, 256, 0, stream>>>(x, w1, b1, a1);
  k_conv2<<<dim3(512, 2), 256, 0, stream>>>(a1, w2t, b2, a2);
  k_conv3<<<dim3(512, 8), 256, 0, stream>>>(a2, w3t, b3, embT);

  TPtrs tp;
  for (int g = 0; g < 4; ++g) {
    tp.in[g]      = (const float*)d_in[7 + 2 * g];
    tp.out[g]     = wt + g * (512 * 768);
    tp.in[4 + g]  = (const float*)d_in[15 + 2 * g];
    tp.out[4 + g] = wt + 4 * (512 * 768) + g * (512 * 1024);
  }
  k_transpose<<<dim3(32, 16, 8), dim3(32, 8), 0, stream>>>(tp);

  const float* wl0[4] = {wt, wt + 393216, wt + 786432, wt + 1179648};
  float* l1base = wt + 1572864;
  const float* wl1[4] = {l1base, l1base + 524288, l1base + 1048576, l1base + 1572864};

  for (int t = 0; t < 16; ++t) {
    int pi = t & 1, po = 1 - pi;
    float* h0i = hc + (pi ? 4 * S : 0);
    float* h0o = hc + (po ? 4 * S : 0);
    float* h1i = hc + S + (pi ? 4 * S : 0);
    float* h1o = hc + S + (po ? 4 * S : 0);
    k_lstm<256><<<256, 512, 0, stream>>>(
        embT + t * 256 * 32, h0i, h0o, hc + 2 * S,
        wl0[0], wl0[1], wl0[2], wl0[3],
        (const float*)d_in[8], (const float*)d_in[10],
        (const float*)d_in[12], (const float*)d_in[14]);
    k_lstm<512><<<256, 512, 0, stream>>>(
        h0o, h1i, h1o, hc + 3 * S,
        wl1[0], wl1[1], wl1[2], wl1[3],
        (const float*)d_in[16], (const float*)d_in[18],
        (const float*)d_in[20], (const float*)d_in[22]);
  }

  k_cls<<<32, 128, 0, stream>>>(hc + S, cw1, cb1, cw2, cb2, cw3, cb3,
                                (float*)d_out);
}

// Round 5
// 673.517 us; speedup vs baseline: 2.5275x; 1.0891x over previous
//
#include <hip/hip_runtime.h>
#include <math.h>

// ---------------------------------------------------------------------------
// conv1: x[512][1][64][64] -> relu -> maxpool2 -> a1[512][16][32][32]
__global__ void k_conv1(const float* __restrict__ x, const float* __restrict__ w,
                        const float* __restrict__ bias, float* __restrict__ out) {
  int idx = blockIdx.x * 256 + threadIdx.x;
  int ox = idx & 31, oy = (idx >> 5) & 31, oc = (idx >> 10) & 15, n = idx >> 14;
  const float* im = x + n * 4096;
  float wv[9];
#pragma unroll
  for (int i = 0; i < 9; ++i) wv[i] = w[oc * 9 + i];
  float bs = bias[oc];
  float m = 0.f;
#pragma unroll
  for (int dy = 0; dy < 2; ++dy)
#pragma unroll
    for (int dx = 0; dx < 2; ++dx) {
      int cy = oy * 2 + dy, cx = ox * 2 + dx;
      float s = bs;
#pragma unroll
      for (int ky = 0; ky < 3; ++ky) {
        int yy = cy + ky - 1;
        if (yy < 0 || yy >= 64) continue;
#pragma unroll
        for (int kx = 0; kx < 3; ++kx) {
          int xx = cx + kx - 1;
          if (xx < 0 || xx >= 64) continue;
          s += im[yy * 64 + xx] * wv[ky * 3 + kx];
        }
      }
      m = fmaxf(m, fmaxf(s, 0.f));
    }
  out[idx] = m;
}

// ---------------------------------------------------------------------------
// weight prep: w2t[c][tap][32oc], w3t[c][tap][256oc]
__global__ void k_prep_w(const float* __restrict__ w2, float* __restrict__ w2t,
                         const float* __restrict__ w3, float* __restrict__ w3t) {
  int id = blockIdx.x * 256 + threadIdx.x;
  if (id < 73728) {
    int ct = id >> 8, oc = id & 255;
    int c = ct / 9, tap = ct - 9 * c;
    w3t[id] = w3[(oc * 32 + c) * 9 + tap];
  }
  if (id < 4608) {
    int ct = id >> 5, oc = id & 31;
    int c = ct / 9, tap = ct - 9 * c;
    w2t[id] = w2[(oc * 16 + c) * 9 + tap];
  }
}

// ---------------------------------------------------------------------------
// conv2: a1[512][16][32][32] -> relu -> maxpool2 -> a2[n][px=256][oc=32]
// (unchanged from round 4)
__global__ __launch_bounds__(256) void k_conv2(
    const float* __restrict__ a1, const float* __restrict__ w2t,
    const float* __restrict__ bias, float* __restrict__ a2) {
  __shared__ __align__(16) float ins[8 * 1024];
  int n = blockIdx.x, ocg = blockIdx.y;
  int tid = threadIdx.x;
  int py = tid >> 4, px = tid & 15;
  int y0 = 2 * py - 1, x0 = 2 * px - 1;
  float acc[16][4] = {};
  const float* wb = w2t + ocg * 16;
  for (int ph = 0; ph < 2; ++ph) {
    __syncthreads();
    const float4* src = (const float4*)(a1 + n * 16384 + ph * 8192);
    for (int i = tid; i < 2048; i += 256) ((float4*)ins)[i] = src[i];
    __syncthreads();
    for (int c = 0; c < 8; ++c) {
      float wv[4][4];
#pragma unroll
      for (int r = 0; r < 4; ++r) {
        int y = y0 + r;
        bool vy = (y >= 0) && (y < 32);
        int yc = vy ? y : 0;
#pragma unroll
        for (int cc = 0; cc < 4; ++cc) {
          int xx = x0 + cc;
          bool vx = (xx >= 0) && (xx < 32);
          int xc = vx ? xx : 0;
          float t = ins[c * 1024 + yc * 32 + xc];
          wv[r][cc] = (vy && vx) ? t : 0.f;
        }
      }
      int ch = ph * 8 + c;
#pragma unroll
      for (int ky = 0; ky < 3; ++ky)
#pragma unroll
        for (int kx = 0; kx < 3; ++kx) {
          const float* w16 = wb + (ch * 9 + ky * 3 + kx) * 32;
#pragma unroll
          for (int i = 0; i < 4; ++i) {
            float vv = wv[(i >> 1) + ky][(i & 1) + kx];
#pragma unroll
            for (int j = 0; j < 16; ++j) acc[j][i] += vv * w16[j];
          }
        }
    }
  }
  const float* bp = bias + ocg * 16;
  float4 o[4];
#pragma unroll
  for (int j = 0; j < 16; ++j) {
    float m = fmaxf(fmaxf(acc[j][0], acc[j][1]), fmaxf(acc[j][2], acc[j][3]));
    ((float*)o)[j] = fmaxf(m + bp[j], 0.f);
  }
  float4* dst = (float4*)(a2 + (size_t)(n * 256 + tid) * 32 + ocg * 16);
#pragma unroll
  for (int q = 0; q < 4; ++q) dst[q] = o[q];
}

// ---------------------------------------------------------------------------
// conv3 v4: a2[n][px][32ch] -> relu -> mean(HW) -> comb0[t][ch][b]
// 512 threads (8 waves x 8 oc each = 64 oc/block), grid (512 n, 4 ocb).
// XOR-swizzled LDS slots (cg ^ ((p>>3)&3)) break the 4-row-strip bank
// collapse (72px stride = 0 mod 32 banks for any 16B-aligned layout).
// Consumer-ordered reads: each float4 read once, used immediately.
__global__ __launch_bounds__(512) void k_conv3(
    const float* __restrict__ a2, const float* __restrict__ w3t,
    const float* __restrict__ bias, float* __restrict__ comb0) {
  __shared__ __align__(16) float ins[324 * 20];  // 25,920 B
  float4* ins4 = (float4*)ins;
  int n = blockIdx.x, ocb = blockIdx.y;
  int tid = threadIdx.x;
  for (int i = tid; i < 1620; i += 512) ins4[i] = float4{0.f, 0.f, 0.f, 0.f};
  int wvid = __builtin_amdgcn_readfirstlane(tid >> 6);  // 8 waves
  int lane = tid & 63;
  int tr = lane >> 4, tc = lane & 15;
  float acc[4][8] = {};
  const float* wbase = w3t + ocb * 64 + wvid * 8;
  const float4* src = (const float4*)(a2 + (size_t)n * 8192);
  for (int hf = 0; hf < 2; ++hf) {
    __syncthreads();
    for (int i = tid; i < 1024; i += 512) {
      int px = i >> 2, cg = i & 3;
      int p = ((px >> 4) + 1) * 18 + (px & 15) + 1;
      ins4[p * 5 + (cg ^ ((p >> 3) & 3))] = src[px * 8 + hf * 4 + cg];
    }
    __syncthreads();
    for (int cg = 0; cg < 4; ++cg) {
      int chb = hf * 16 + cg * 4;
#pragma unroll
      for (int dr = 0; dr < 6; ++dr) {
#pragma unroll
        for (int dc = 0; dc < 3; ++dc) {
          int pp = (4 * tr + dr) * 18 + tc + dc;
          float4 v = ins4[pp * 5 + (cg ^ ((pp >> 3) & 3))];
#pragma unroll
          for (int c = 0; c < 4; ++c) {
            float vv = ((const float*)&v)[c];
            const int ilo = (dr - 2 < 0) ? 0 : dr - 2;
            const int ihi = (dr < 3) ? dr : 3;
#pragma unroll
            for (int i = ilo; i <= ihi; ++i) {
              const float* w8 = wbase + (((chb + c) * 9 + (dr - i) * 3 + dc) * 256);
#pragma unroll
              for (int j = 0; j < 8; ++j) acc[i][j] += vv * w8[j];
            }
          }
        }
      }
    }
  }
  const float* bp = bias + ocb * 64 + wvid * 8;
  int bb = n >> 4, tt = n & 15;
#pragma unroll
  for (int j = 0; j < 8; ++j) {
    float bj = bp[j];
    float s = 0.f;
#pragma unroll
    for (int i = 0; i < 4; ++i) s += fmaxf(acc[i][j] + bj, 0.f);
#pragma unroll
    for (int off = 32; off; off >>= 1) s += __shfl_down(s, off, 64);
    if (lane == 0) {
      int oc = ocb * 64 + wvid * 8 + j;
      comb0[(size_t)(tt * 768 + oc) * 32 + bb] = s * (1.f / 256.f);
    }
  }
}

// ---------------------------------------------------------------------------
// weight transpose: W[fan][512] -> WT[512][fan], 8 arrays in one launch
struct TPtrs { const float* in[8]; float* out[8]; };

__global__ void k_transpose(TPtrs p) {
  __shared__ float tile[32][33];
  int z = blockIdx.z;
  int fan = (z < 4) ? 768 : 1024;
  int k0 = blockIdx.x * 32, h0 = blockIdx.y * 32;
  if (k0 >= fan) return;
  const float* in = p.in[z];
  float* out = p.out[z];
  int tx = threadIdx.x, ty = threadIdx.y;  // 32 x 8
  for (int r = 0; r < 32; r += 8)
    tile[ty + r][tx] = in[(k0 + ty + r) * 512 + h0 + tx];
  __syncthreads();
  for (int r = 0; r < 32; r += 8)
    out[(h0 + ty + r) * fan + k0 + tx] = tile[tx][ty + r];
}

// ---------------------------------------------------------------------------
// LSTM v3: grid 512 blocks (1 per h), 512 threads = (kq 16, gate c 4, bq 8).
// Batch held in registers (acc[4]): each ds_read_b128 of weights feeds 16
// FMAs; activations via one coalesced dwordx4 per k from the contiguous
// comb[FAN][32] buffer (no x/h pointer select). Partial sums reduced in LDS.
template <int IN>
__global__ __launch_bounds__(512) void k_lstm(
    const float* __restrict__ comb,   // [FAN][32] for this (layer, step)
    float* __restrict__ houtA, float* __restrict__ houtB,
    float* __restrict__ cT,
    const float* __restrict__ WfT, const float* __restrict__ WiT,
    const float* __restrict__ WgT, const float* __restrict__ WoT,
    const float* __restrict__ bf, const float* __restrict__ bi,
    const float* __restrict__ bg, const float* __restrict__ bo) {
  constexpr int FAN = IN + 512;
  constexpr int PR = FAN + 4;        // padded row: 4c*4 dword offset per gate
  constexpr int KT = FAN / 16;       // k per thread (48 or 64)
  __shared__ __align__(16) float wl[4 * PR];
  __shared__ __align__(16) float gsum[4][16][36];
  __shared__ float pre[4][33];
  const int tid = threadIdx.x;
  const int h = blockIdx.x;
  if (tid < FAN / 4) {
    ((float4*)(wl + 0 * PR))[tid] = ((const float4*)(WfT + h * FAN))[tid];
    ((float4*)(wl + 1 * PR))[tid] = ((const float4*)(WiT + h * FAN))[tid];
    ((float4*)(wl + 2 * PR))[tid] = ((const float4*)(WgT + h * FAN))[tid];
    ((float4*)(wl + 3 * PR))[tid] = ((const float4*)(WoT + h * FAN))[tid];
  }
  __syncthreads();
  const int kq = tid >> 5, c = (tid >> 3) & 3, bq = tid & 7;
  const int kbase = kq * KT;
  const float4* w4 = (const float4*)(wl + c * PR + kbase);
  const float4* a4 = (const float4*)comb + bq;  // element k at a4[k*8]
  float acc0 = 0.f, acc1 = 0.f, acc2 = 0.f, acc3 = 0.f;
#pragma unroll
  for (int kk = 0; kk < KT / 4; ++kk) {
    float4 w = w4[kk];
#pragma unroll
    for (int j = 0; j < 4; ++j) {
      float wj = ((const float*)&w)[j];
      float4 a = a4[(size_t)(kbase + kk * 4 + j) * 8];
      acc0 += wj * a.x; acc1 += wj * a.y; acc2 += wj * a.z; acc3 += wj * a.w;
    }
  }
  ((float4*)&gsum[c][kq][0])[bq] = float4{acc0, acc1, acc2, acc3};
  __syncthreads();
  if (tid < 128) {
    int cc = tid >> 5, b = tid & 31;
    float s = 0.f;
#pragma unroll
    for (int q = 0; q < 16; ++q) s += gsum[cc][q][b];
    pre[cc][b] = s;
  }
  __syncthreads();
  if (tid < 32) {
    int b = tid;
    float fp = pre[0][b] + bf[h];
    float ip = pre[1][b] + bi[h];
    float gp = pre[2][b] + bg[h];
    float op = pre[3][b] + bo[h];
    float ft = 1.f / (1.f + expf(-fp));
    float it = 1.f / (1.f + expf(-ip));
    float gt = tanhf(gp);
    float ot = 1.f / (1.f + expf(-op));
    float cn = ft * cT[h * 32 + b] + it * gt;
    cT[h * 32 + b] = cn;
    float hn = ot * tanhf(cn);
    houtA[h * 32 + b] = hn;
    houtB[h * 32 + b] = hn;
  }
}

// ---------------------------------------------------------------------------
// classifier: input h1T layout [h][b] (a comb slice)
__global__ void k_cls(const float* __restrict__ h1T, const float* __restrict__ cw1,
                      const float* __restrict__ cb1, const float* __restrict__ cw2,
                      const float* __restrict__ cb2, const float* __restrict__ cw3,
                      const float* __restrict__ cb3, float* __restrict__ out) {
  __shared__ float hv[512];
  __shared__ float y1[128];
  __shared__ float y2[64];
  int b = blockIdx.x, tid = threadIdx.x;
  for (int i = tid; i < 512; i += 128) hv[i] = h1T[i * 32 + b];
  __syncthreads();
  float s = cb1[tid];
  for (int k = 0; k < 512; ++k) s += hv[k] * cw1[k * 128 + tid];
  y1[tid] = fmaxf(s, 0.f);
  __syncthreads();
  if (tid < 64) {
    float s2 = cb2[tid];
    for (int k = 0; k < 128; ++k) s2 += y1[k] * cw2[k * 64 + tid];
    y2[tid] = fmaxf(s2, 0.f);
  }
  __syncthreads();
  if (tid < 6) {
    float s3 = cb3[tid];
    for (int k = 0; k < 64; ++k) s3 += y2[k] * cw3[k * 6 + tid];
    out[b * 6 + tid] = s3;
  }
}

// ---------------------------------------------------------------------------
// Workspace (floats):
//  region0 [0..8,388,608) = a1 (conv1 out, dead after conv2); then reused:
//    wt    @ 0          [3,670,016]  (k_transpose, after conv2)
//    comb0 @ 3,670,016  [17*768*32  = 417,792]   comb0[t] = [emb(t), h0(t-1)]
//    comb1 @ 4,087,808  [17*1024*32 = 557,056]   comb1[t] = [h0(t), h1(t-1)]
//    c0    @ 4,644,864  [16,384];  c1 @ 4,661,248 [16,384]
//  a2  @ 8,388,608  [4,194,304]   layout [n][px][oc]
//  w2t @ 12,582,912 [4,608];  w3t @ 12,587,520 [73,728]  -> end 50.6 MB
extern "C" void kernel_launch(void* const* d_in, const int* in_sizes, int n_in,
                              void* d_out, int out_size, void* d_ws, size_t ws_size,
                              hipStream_t stream) {
  const float* x  = (const float*)d_in[0];
  const float* w1 = (const float*)d_in[1];
  const float* b1 = (const float*)d_in[2];
  const float* w2 = (const float*)d_in[3];
  const float* b2 = (const float*)d_in[4];
  const float* w3 = (const float*)d_in[5];
  const float* b3 = (const float*)d_in[6];
  const float* cw1 = (const float*)d_in[23];
  const float* cb1 = (const float*)d_in[24];
  const float* cw2 = (const float*)d_in[25];
  const float* cb2 = (const float*)d_in[26];
  const float* cw3 = (const float*)d_in[27];
  const float* cb3 = (const float*)d_in[28];

  float* ws = (float*)d_ws;
  float* a1    = ws;
  float* wt    = ws;
  float* comb0 = ws + 3670016;
  float* comb1 = ws + 4087808;
  float* c0    = ws + 4644864;
  float* c1    = ws + 4661248;
  float* a2    = ws + 8388608;
  float* w2t   = ws + 12582912;
  float* w3t   = ws + 12587520;
  const int C0 = 768 * 32, C1 = 1024 * 32;

  k_prep_w<<<288, 256, 0, stream>>>(w2, w2t, w3, w3t);
  k_conv1<<<32768, 256, 0, stream>>>(x, w1, b1, a1);
  k_conv2<<<dim3(512, 2), 256, 0, stream>>>(a1, w2t, b2, a2);
  // a1 now dead; everything below may write region0

  // zero initial h0 (comb0[0] h-part), h1 (comb1[0] h-part), c0+c1
  hipMemsetAsync(comb0 + 256 * 32, 0, (size_t)512 * 32 * 4, stream);
  hipMemsetAsync(comb1 + 512 * 32, 0, (size_t)512 * 32 * 4, stream);
  hipMemsetAsync(c0, 0, (size_t)2 * 512 * 32 * 4, stream);  // c0 and c1 contiguous

  k_conv3<<<dim3(512, 4), 512, 0, stream>>>(a2, w3t, b3, comb0);

  TPtrs tp;
  for (int g = 0; g < 4; ++g) {
    tp.in[g]      = (const float*)d_in[7 + 2 * g];
    tp.out[g]     = wt + g * (512 * 768);
    tp.in[4 + g]  = (const float*)d_in[15 + 2 * g];
    tp.out[4 + g] = wt + 4 * (512 * 768) + g * (512 * 1024);
  }
  k_transpose<<<dim3(32, 16, 8), dim3(32, 8), 0, stream>>>(tp);

  const float* wl0[4] = {wt, wt + 393216, wt + 786432, wt + 1179648};
  float* l1base = wt + 1572864;
  const float* wl1[4] = {l1base, l1base + 524288, l1base + 1048576, l1base + 1572864};

  for (int t = 0; t < 16; ++t) {
    // layer0: reads comb0[t]; h0(t) -> comb0[t+1][256..768) and comb1[t][0..512)
    k_lstm<256><<<512, 512, 0, stream>>>(
        comb0 + (size_t)t * C0,
        comb0 + (size_t)(t + 1) * C0 + 256 * 32,
        comb1 + (size_t)t * C1,
        c0, wl0[0], wl0[1], wl0[2], wl0[3],
        (const float*)d_in[8], (const float*)d_in[10],
        (const float*)d_in[12], (const float*)d_in[14]);
    // layer1: reads comb1[t]; h1(t) -> comb1[t+1][512..1024) (dup write)
    k_lstm<512><<<512, 512, 0, stream>>>(
        comb1 + (size_t)t * C1,
        comb1 + (size_t)(t + 1) * C1 + 512 * 32,
        comb1 + (size_t)(t + 1) * C1 + 512 * 32,
        c1, wl1[0], wl1[1], wl1[2], wl1[3],
        (const float*)d_in[16], (const float*)d_in[18],
        (const float*)d_in[20], (const float*)d_in[22]);
  }

  k_cls<<<32, 128, 0, stream>>>(comb1 + (size_t)16 * C1 + 512 * 32,
                                cw1, cb1, cw2, cb2, cw3, cb3, (float*)d_out);
}